// Round 2
// baseline (1618.917 us; speedup 1.0000x reference)
//
#include <hip/hip_runtime.h>
#include <hip/hip_bf16.h>
#include <hip/hip_fp16.h>

#define NPTS 4096
#define KNB  20
#define EPSB 1e-5f

typedef _Float16 half8 __attribute__((ext_vector_type(8)));
typedef float    f32x4 __attribute__((ext_vector_type(4)));

__device__ __forceinline__ f32x4 mfma16(half8 a, half8 b, f32x4 c){
  return __builtin_amdgcn_mfma_f32_16x16x32_f16(a, b, c, 0, 0, 0);
}

// A fragment from LDS, row-major [rows][C] fp16, XOR-swizzled by (row&7)<<3 elements.
__device__ __forceinline__ half8 loadA_lds(const _Float16* buf, int C, int mt, int ks, int lane){
  int row = mt*16 + (lane & 15);
  int k0  = ks*32 + (lane >> 4)*8;
  int e   = (row*C + k0) ^ ((row & 7) << 3);
  return *reinterpret_cast<const half8*>(&buf[e]);
}

// B fragment from global, WT is [N_out][K] fp16 (pre-transposed weight)
__device__ __forceinline__ half8 loadB_g(const _Float16* WT, int K, int nt, int ks, int lane){
  int col = nt*16 + (lane & 15);
  int k0  = ks*32 + (lane >> 4)*8;
  return *reinterpret_cast<const half8*>(&WT[col*K + k0]);
}

// C/D layout (verified m89): col = lane&15, row = (lane>>4)*4 + r
__device__ __forceinline__ void storeTile(_Float16* buf, int C, int mt, int nt, int lane,
                                          f32x4 acc, float sc, float bs){
  int col = nt*16 + (lane & 15);
  #pragma unroll
  for (int r = 0; r < 4; ++r){
    int row = mt*16 + (lane >> 4)*4 + r;
    float v = acc[r]*sc + bs;
    v = v > 0.f ? v : 0.2f*v;
    buf[(row*C + col) ^ ((row & 7) << 3)] = (_Float16)v;
  }
}

__device__ __forceinline__ float hval(const _Float16* buf, int C, int r, int c){
  return (float)buf[(r*C + c) ^ ((r & 7) << 3)];
}

// ---------------- KNN ----------------
// Per wave: 2 rows. Per lane: 64 candidates j = t*64+lane, distances in VGPRs.
// Selection: wave argmax butterfly; winner lane promotes its 2nd-best (rescan only
// on double-win, ~3x/row). launch_bounds(512,2) -> 256 VGPR cap, no spill.
__global__ __launch_bounds__(512, 2)
void knn_kernel(const float* __restrict__ x, int* __restrict__ idx_out){
  __shared__ float4 spts[NPTS];           // (x,y,z,xx) 64KB
  int b  = blockIdx.x >> 8;               // 256 row-blocks per batch
  int r0 = (blockIdx.x & 255) << 4;       // 16 rows per block
  const float* xb = x + (size_t)b*NPTS*3;
  for (int t = threadIdx.x; t < NPTS; t += 512){
    float px = xb[t*3+0], py = xb[t*3+1], pz = xb[t*3+2];
    spts[t] = make_float4(px, py, pz, px*px + py*py + pz*pz);
  }
  __syncthreads();
  int wave = threadIdx.x >> 6, lane = threadIdx.x & 63;
  #pragma unroll 1
  for (int rr = 0; rr < 2; ++rr){
    int i = r0 + wave*2 + rr;
    float4 pi = spts[i];
    float v[64];
    float best = -INFINITY, second = -INFINITY;
    int bidx = 0, sidx = 0;
    #pragma unroll
    for (int t = 0; t < 64; ++t){
      int j = (t << 6) + lane;
      float4 q = spts[j];
      float d = 2.f*(pi.x*q.x + pi.y*q.y + pi.z*q.z) - pi.w - q.w;  // neg sq dist
      v[t] = d;
      if (d > best){ second = best; sidx = bidx; best = d; bidx = j; }
      else if (d > second){ second = d; sidx = j; }
    }
    unsigned rem_lo = 0, rem_hi = 0;      // removed-candidate bitmask (per lane)
    size_t obase = ((size_t)b*NPTS + i)*KNB;
    #pragma unroll 1
    for (int kk = 0; kk < KNB; ++kk){
      float bv = best; int bi = bidx;
      #pragma unroll
      for (int m = 32; m > 0; m >>= 1){      // argmax, smallest-index tie-break
        float ov = __shfl_xor(bv, m);
        int   oi = __shfl_xor(bi, m);
        if (ov > bv || (ov == bv && oi < bi)){ bv = ov; bi = oi; }
      }
      if (lane == 0) idx_out[obase + kk] = bi;
      if ((bi & 63) == lane){                // this lane's best won: remove it
        int tw = bi >> 6;
        if (tw < 32) rem_lo |= (1u << tw); else rem_hi |= (1u << (tw - 32));
        if (second != -INFINITY){            // promote cached 2nd-best
          best = second; bidx = sidx; second = -INFINITY;
        } else {                             // rare: rebuild top-2 vs removed mask
          best = -INFINITY; second = -INFINITY; bidx = 0; sidx = 0;
          #pragma unroll
          for (int t = 0; t < 64; ++t){
            unsigned rm = (t < 32) ? (rem_lo & (1u << t)) : (rem_hi & (1u << (t - 32)));
            float d = rm ? -INFINITY : v[t];
            int j = (t << 6) + lane;
            if (d > best){ second = best; sidx = bidx; best = d; bidx = j; }
            else if (d > second){ second = d; sidx = j; }
          }
        }
      }
    }
  }
}

// ---------------- weight prep: fp32 [K][O] -> fp16 [O][K] ----------------
__global__ __launch_bounds__(256)
void prep_kernel(const float* __restrict__ W2, const float* __restrict__ W3,
                 const float* __restrict__ W4, const float* __restrict__ W5,
                 _Float16* __restrict__ W2T, _Float16* __restrict__ W3T,
                 _Float16* __restrict__ W4T, _Float16* __restrict__ W5T){
  int t = blockIdx.x*256 + threadIdx.x;
  if (t < 4096){ int o=t>>6, k=t&63;                W2T[t] = (_Float16)W2[k*64+o]; }
  else if (t < 12288){ int u=t-4096;  int o=u>>6, k=u&63;   W3T[u] = (_Float16)W3[k*128+o]; }
  else if (t < 45056){ int u=t-12288; int o=u>>7, k=u&127;  W4T[u] = (_Float16)W4[k*256+o]; }
  else if (t < 569344){ int u=t-45056; int o=u>>9, k=u&511; W5T[u] = (_Float16)W5[k*1024+o]; }
}

// ---------------- fused edge layers 1-4 ----------------
__global__ __launch_bounds__(256)
void edge_kernel(const float* __restrict__ x, const int* __restrict__ knn,
                 const float* __restrict__ W1, const float* __restrict__ g1, const float* __restrict__ b1,
                 const _Float16* __restrict__ W2T, const float* __restrict__ g2, const float* __restrict__ b2,
                 const _Float16* __restrict__ W3T, const float* __restrict__ g3, const float* __restrict__ b3,
                 const _Float16* __restrict__ W4T, const float* __restrict__ g4, const float* __restrict__ b4,
                 _Float16* __restrict__ hc){
  __shared__ float h0[80][8];
  __shared__ __align__(16) _Float16 hb1[80*64];
  __shared__ __align__(16) _Float16 hb2[80*64];
  __shared__ __align__(16) _Float16 hb3[80*128];
  const float rs = 1.f / sqrtf(1.f + EPSB);
  int gp0 = blockIdx.x << 2;              // 4 points per block
  int b   = gp0 >> 12;
  int n0  = gp0 & (NPTS-1);
  const float* xb = x + (size_t)b*NPTS*3;
  if (threadIdx.x < 80){
    int p = threadIdx.x / 20, k = threadIdx.x % 20;
    int n = n0 + p;
    int nb = knn[((size_t)b*NPTS + n)*KNB + k];
    h0[threadIdx.x][0] = xb[nb*3+0];
    h0[threadIdx.x][1] = xb[nb*3+1];
    h0[threadIdx.x][2] = xb[nb*3+2];
    h0[threadIdx.x][3] = xb[n*3+0];
    h0[threadIdx.x][4] = xb[n*3+1];
    h0[threadIdx.x][5] = xb[n*3+2];
  }
  __syncthreads();
  int wave = threadIdx.x >> 6, lane = threadIdx.x & 63;
  // layer 1: [80,6]@[6,64], fp32 VALU
  {
    int col = threadIdx.x & 63;
    float sc = g1[col]*rs, bs = b1[col];
    float w0=W1[col], w1=W1[64+col], w2=W1[128+col], w3=W1[192+col], w4=W1[256+col], w5=W1[320+col];
    #pragma unroll 1
    for (int r = threadIdx.x >> 6; r < 80; r += 4){
      float a = h0[r][0]*w0 + h0[r][1]*w1 + h0[r][2]*w2 + h0[r][3]*w3 + h0[r][4]*w4 + h0[r][5]*w5;
      float vv = a*sc + bs; vv = vv>0.f ? vv : 0.2f*vv;
      hb1[((r<<6)+col) ^ ((r&7)<<3)] = (_Float16)vv;
    }
  }
  __syncthreads();
  // layer 2: [80,64]@[64,64] — wave owns N-tile `wave`
  {
    int nt = wave;
    int col = (nt<<4) + (lane&15);
    float sc = g2[col]*rs, bs = b2[col];
    half8 bf0 = loadB_g(W2T, 64, nt, 0, lane);
    half8 bf1 = loadB_g(W2T, 64, nt, 1, lane);
    #pragma unroll
    for (int mt = 0; mt < 5; ++mt){
      f32x4 acc = {0.f,0.f,0.f,0.f};
      acc = mfma16(loadA_lds(hb1,64,mt,0,lane), bf0, acc);
      acc = mfma16(loadA_lds(hb1,64,mt,1,lane), bf1, acc);
      storeTile(hb2, 64, mt, nt, lane, acc, sc, bs);
    }
  }
  __syncthreads();
  // layer 3: [80,64]@[64,128] — wave owns N-tiles 2w,2w+1
  {
    #pragma unroll
    for (int tt = 0; tt < 2; ++tt){
      int nt = (wave<<1) + tt;
      int col = (nt<<4) + (lane&15);
      float sc = g3[col]*rs, bs = b3[col];
      half8 bf0 = loadB_g(W3T, 64, nt, 0, lane);
      half8 bf1 = loadB_g(W3T, 64, nt, 1, lane);
      #pragma unroll
      for (int mt = 0; mt < 5; ++mt){
        f32x4 acc = {0.f,0.f,0.f,0.f};
        acc = mfma16(loadA_lds(hb2,64,mt,0,lane), bf0, acc);
        acc = mfma16(loadA_lds(hb2,64,mt,1,lane), bf1, acc);
        storeTile(hb3, 128, mt, nt, lane, acc, sc, bs);
      }
    }
  }
  __syncthreads();
  // max-over-K epilogues for x1,x2,x3
  {
    int p = threadIdx.x >> 6, c = threadIdx.x & 63;
    float m1=-INFINITY, m2=-INFINITY, m3a=-INFINITY, m3b=-INFINITY;
    #pragma unroll 1
    for (int k = 0; k < KNB; ++k){
      int r = p*20 + k;
      m1  = fmaxf(m1,  hval(hb1, 64,  r, c));
      m2  = fmaxf(m2,  hval(hb2, 64,  r, c));
      m3a = fmaxf(m3a, hval(hb3, 128, r, c));
      m3b = fmaxf(m3b, hval(hb3, 128, r, c+64));
    }
    size_t o = (size_t)(gp0 + p) * 512;
    hc[o + c]        = (_Float16)m1;
    hc[o + 64  + c]  = (_Float16)m2;
    hc[o + 128 + c]  = (_Float16)m3a;
    hc[o + 192 + c]  = (_Float16)m3b;
  }
  __syncthreads();
  // layer 4: [80,128]@[128,256] in 4 chunks of 64 cols (hb1 reused as chunk buf)
  #pragma unroll 1
  for (int ch = 0; ch < 4; ++ch){
    {
      int ntg = (ch<<2) + wave;
      int col = (ntg<<4) + (lane&15);
      float sc = g4[col]*rs, bs = b4[col];
      half8 bw[4];
      #pragma unroll
      for (int ks = 0; ks < 4; ++ks) bw[ks] = loadB_g(W4T, 128, ntg, ks, lane);
      #pragma unroll
      for (int mt = 0; mt < 5; ++mt){
        f32x4 acc = {0.f,0.f,0.f,0.f};
        #pragma unroll
        for (int ks = 0; ks < 4; ++ks)
          acc = mfma16(loadA_lds(hb3,128,mt,ks,lane), bw[ks], acc);
        storeTile(hb1, 64, mt, wave, lane, acc, sc, bs);
      }
    }
    __syncthreads();
    {
      int p = threadIdx.x >> 6, c = threadIdx.x & 63;
      float m = -INFINITY;
      #pragma unroll 1
      for (int k = 0; k < KNB; ++k)
        m = fmaxf(m, hval(hb1, 64, p*20 + k, c));
      hc[(size_t)(gp0 + p)*512 + 256 + (ch<<6) + c] = (_Float16)m;
    }
    __syncthreads();
  }
}

// ---------------- layer 5 GEMM + pooling partials ----------------
__global__ __launch_bounds__(256)
void gemm5_kernel(const _Float16* __restrict__ hc, const _Float16* __restrict__ W5T,
                  const float* __restrict__ g5, const float* __restrict__ b5,
                  float* __restrict__ red){
  __shared__ __align__(16) _Float16 sA[64*512];   // 64KB
  int rowblk = blockIdx.x >> 2;
  int colblk = blockIdx.x & 3;
  int row0 = rowblk << 6;
  // stage A chunk: swizzled source -> linear LDS (so swizzled reads see hc[row][k])
  #pragma unroll 1
  for (int it = 0; it < 16; ++it){
    int eoff = it*2048 + threadIdx.x*8;
    int row = eoff >> 9;
    int ine = eoff & 511;
    half8 vsrc = *reinterpret_cast<const half8*>(
        &hc[(size_t)(row0 + row)*512 + (ine ^ ((row & 7) << 3))]);
    *reinterpret_cast<half8*>(&sA[(row << 9) + ine]) = vsrc;
  }
  __syncthreads();
  int wave = threadIdx.x >> 6, lane = threadIdx.x & 63;
  f32x4 acc[4][4] = {};
  #pragma unroll 1
  for (int ks = 0; ks < 16; ++ks){
    half8 af[4];
    #pragma unroll
    for (int mt = 0; mt < 4; ++mt) af[mt] = loadA_lds(sA, 512, mt, ks, lane);
    #pragma unroll
    for (int nt = 0; nt < 4; ++nt){
      int ntg = (colblk<<4) + (wave<<2) + nt;
      half8 bf = loadB_g(W5T, 512, ntg, ks, lane);
      #pragma unroll
      for (int mt = 0; mt < 4; ++mt)
        acc[mt][nt] = mfma16(af[mt], bf, acc[mt][nt]);
    }
  }
  int batch = row0 >> 12;
  int chunk = (row0 & (NPTS-1)) >> 6;
  const float rs = 1.f/sqrtf(1.f+EPSB);
  #pragma unroll
  for (int nt = 0; nt < 4; ++nt){
    int ntg = (colblk<<4) + (wave<<2) + nt;
    int colg = (ntg<<4) + (lane & 15);
    float sc = g5[colg]*rs, bs = b5[colg];
    float vmax = -INFINITY, vsum = 0.f;
    #pragma unroll
    for (int mt = 0; mt < 4; ++mt){
      #pragma unroll
      for (int r = 0; r < 4; ++r){
        float vv = acc[mt][nt][r]*sc + bs;
        vv = vv>0.f ? vv : 0.2f*vv;
        vmax = fmaxf(vmax, vv); vsum += vv;
      }
    }
    vmax = fmaxf(vmax, __shfl_xor(vmax, 16)); vsum += __shfl_xor(vsum, 16);
    vmax = fmaxf(vmax, __shfl_xor(vmax, 32)); vsum += __shfl_xor(vsum, 32);
    if ((lane >> 4) == 0){
      size_t base = (size_t)((batch<<6) + chunk)*2048;
      red[base + colg] = vmax;
      red[base + 1024 + colg] = vsum;
    }
  }
}

__global__ __launch_bounds__(256)
void reduce_g_kernel(const float* __restrict__ red, float* __restrict__ g){
  int t = blockIdx.x*256 + threadIdx.x;   // 8192
  int b = t >> 10, col = t & 1023;
  float m = -INFINITY, s = 0.f;
  #pragma unroll 4
  for (int c = 0; c < 64; ++c){
    size_t base = (size_t)((b<<6)+c)*2048;
    m = fmaxf(m, red[base + col]);
    s += red[base + 1024 + col];
  }
  g[(b<<11) + col]        = m;
  g[(b<<11) + 1024 + col] = s * (1.f/4096.f);
}

// ---------------- head MLP ----------------
__global__ __launch_bounds__(256)
void fc1_kernel(const float* __restrict__ g, const float* __restrict__ L1,
                const float* __restrict__ g6, const float* __restrict__ b6,
                float* __restrict__ f1){
  int t = blockIdx.x*256 + threadIdx.x;   // 4096
  int b = t >> 9, o = t & 511;
  const float* gb = g + (b<<11);
  float acc = 0.f;
  #pragma unroll 8
  for (int c = 0; c < 2048; ++c) acc += gb[c]*L1[c*512 + o];
  float v = acc*(g6[o]/sqrtf(1.f+EPSB)) + b6[o];
  f1[t] = v>0.f ? v : 0.2f*v;
}

__global__ __launch_bounds__(256)
void fc2_kernel(const float* __restrict__ f1, const float* __restrict__ L2, const float* __restrict__ L2b,
                const float* __restrict__ g7, const float* __restrict__ b7, float* __restrict__ f2){
  int t = blockIdx.x*256 + threadIdx.x;   // 2048
  int b = t >> 8, o = t & 255;
  const float* fb = f1 + (b<<9);
  float acc = 0.f;
  #pragma unroll 8
  for (int c = 0; c < 512; ++c) acc += fb[c]*L2[c*256 + o];
  float v = (acc + L2b[o])*(g7[o]/sqrtf(1.f+EPSB)) + b7[o];
  f2[t] = v>0.f ? v : 0.2f*v;
}

__global__ __launch_bounds__(256)
void fc3_kernel(const float* __restrict__ f2, const float* __restrict__ L3, const float* __restrict__ L3b,
                float* __restrict__ out){
  int t = blockIdx.x*256 + threadIdx.x;   // 1024
  int b = t >> 7, o = t & 127;
  const float* fb = f2 + (b<<8);
  float acc = 0.f;
  #pragma unroll 8
  for (int c = 0; c < 256; ++c) acc += fb[c]*L3[c*128 + o];
  out[t] = acc + L3b[o];
}

extern "C" void kernel_launch(void* const* d_in, const int* in_sizes, int n_in,
                              void* d_out, int out_size, void* d_ws, size_t ws_size,
                              hipStream_t stream){
  const float* x  = (const float*)d_in[0];
  const float* W1 = (const float*)d_in[1];
  const float* g1 = (const float*)d_in[2];  const float* b1 = (const float*)d_in[3];
  const float* W2 = (const float*)d_in[4];
  const float* g2 = (const float*)d_in[5];  const float* b2 = (const float*)d_in[6];
  const float* W3 = (const float*)d_in[7];
  const float* g3 = (const float*)d_in[8];  const float* b3 = (const float*)d_in[9];
  const float* W4 = (const float*)d_in[10];
  const float* g4 = (const float*)d_in[11]; const float* b4 = (const float*)d_in[12];
  const float* W5 = (const float*)d_in[13];
  const float* g5 = (const float*)d_in[14]; const float* b5 = (const float*)d_in[15];
  const float* L1 = (const float*)d_in[16];
  const float* g6 = (const float*)d_in[17]; const float* b6 = (const float*)d_in[18];
  const float* L2 = (const float*)d_in[19]; const float* L2b = (const float*)d_in[20];
  const float* g7 = (const float*)d_in[21]; const float* b7 = (const float*)d_in[22];
  const float* L3 = (const float*)d_in[23]; const float* L3b = (const float*)d_in[24];

  char* ws = (char*)d_ws;
  int*      idx  = (int*)(ws + 0);                 // 2,621,440 B
  _Float16* hc   = (_Float16*)(ws + 2621440);      // 33,554,432 B
  _Float16* W2T  = (_Float16*)(ws + 36175872);     // 8,192 B
  _Float16* W3T  = (_Float16*)(ws + 36184064);     // 16,384 B
  _Float16* W4T  = (_Float16*)(ws + 36200448);     // 65,536 B
  _Float16* W5T  = (_Float16*)(ws + 36265984);     // 1,048,576 B
  float*    red  = (float*)(ws + 37314560);        // 4,194,304 B
  float*    gbuf = (float*)(ws + 41508864);        // 65,536 B
  float*    f1   = (float*)(ws + 41574400);        // 16,384 B
  float*    f2   = (float*)(ws + 41590784);        // 8,192 B

  knn_kernel<<<2048, 512, 0, stream>>>(x, idx);
  prep_kernel<<<2224, 256, 0, stream>>>(W2, W3, W4, W5, W2T, W3T, W4T, W5T);
  edge_kernel<<<8192, 256, 0, stream>>>(x, idx, W1, g1, b1, W2T, g2, b2,
                                        W3T, g3, b3, W4T, g4, b4, hc);
  gemm5_kernel<<<2048, 256, 0, stream>>>(hc, W5T, g5, b5, red);
  reduce_g_kernel<<<32, 256, 0, stream>>>(red, gbuf);
  fc1_kernel<<<16, 256, 0, stream>>>(gbuf, L1, g6, b6, f1);
  fc2_kernel<<<8, 256, 0, stream>>>(f1, L2, L2b, g7, b7, f2);
  fc3_kernel<<<4, 256, 0, stream>>>(f2, L3, L3b, (float*)d_out);
}

// Round 3
// 760.600 us; speedup vs baseline: 2.1285x; 2.1285x over previous
//
#include <hip/hip_runtime.h>
#include <hip/hip_bf16.h>
#include <hip/hip_fp16.h>

#define NPTS 4096
#define KNB  20
#define EPSB 1e-5f

typedef _Float16 half8 __attribute__((ext_vector_type(8)));
typedef float    f32x4 __attribute__((ext_vector_type(4)));

__device__ __forceinline__ f32x4 mfma16(half8 a, half8 b, f32x4 c){
  return __builtin_amdgcn_mfma_f32_16x16x32_f16(a, b, c, 0, 0, 0);
}

// A fragment from LDS, row-major [rows][C] fp16, XOR-swizzled by (row&7)<<3 elements.
__device__ __forceinline__ half8 loadA_lds(const _Float16* buf, int C, int mt, int ks, int lane){
  int row = mt*16 + (lane & 15);
  int k0  = ks*32 + (lane >> 4)*8;
  int e   = (row*C + k0) ^ ((row & 7) << 3);
  return *reinterpret_cast<const half8*>(&buf[e]);
}

// B fragment from global, WT is [N_out][K] fp16 (pre-transposed weight)
__device__ __forceinline__ half8 loadB_g(const _Float16* WT, int K, int nt, int ks, int lane){
  int col = nt*16 + (lane & 15);
  int k0  = ks*32 + (lane >> 4)*8;
  return *reinterpret_cast<const half8*>(&WT[col*K + k0]);
}

// C/D layout (verified m89): col = lane&15, row = (lane>>4)*4 + r
__device__ __forceinline__ void storeTile(_Float16* buf, int C, int mt, int nt, int lane,
                                          f32x4 acc, float sc, float bs){
  int col = nt*16 + (lane & 15);
  #pragma unroll
  for (int r = 0; r < 4; ++r){
    int row = mt*16 + (lane >> 4)*4 + r;
    float v = acc[r]*sc + bs;
    v = v > 0.f ? v : 0.2f*v;
    buf[(row*C + col) ^ ((row & 7) << 3)] = (_Float16)v;
  }
}

__device__ __forceinline__ float hval(const _Float16* buf, int C, int r, int c){
  return (float)buf[(r*C + c) ^ ((r & 7) << 3)];
}

// ---------------- KNN ----------------
// Wave per 2 rows. Per lane: candidates j = t*64+lane, t=0..63, distances streamed
// from LDS (never stored per-lane -> no scratch). Per-lane top-3 cache; butterfly
// argmax across lanes per neighbor; winner promotes cache, rebuilds from LDS only
// when cache exhausted (expected ~0.3x per row).
__global__ __launch_bounds__(512)
void knn_kernel(const float* __restrict__ x, int* __restrict__ idx_out){
  __shared__ float4 spts[NPTS];           // (x,y,z,xx) 64KB
  int b  = blockIdx.x >> 8;               // 256 row-blocks per batch
  int r0 = (blockIdx.x & 255) << 4;       // 16 rows per block
  const float* xb = x + (size_t)b*NPTS*3;
  for (int t = threadIdx.x; t < NPTS; t += 512){
    float px = xb[t*3+0], py = xb[t*3+1], pz = xb[t*3+2];
    spts[t] = make_float4(px, py, pz, px*px + py*py + pz*pz);
  }
  __syncthreads();
  int wave = threadIdx.x >> 6, lane = threadIdx.x & 63;
  #pragma unroll 1
  for (int rr = 0; rr < 2; ++rr){
    int i = r0 + wave*2 + rr;
    float4 pi = spts[i];
    float b1 = -INFINITY, b2 = -INFINITY, b3 = -INFINITY;
    int   i1 = 0, i2 = 0, i3 = 0;
    #pragma unroll 8
    for (int t = 0; t < 64; ++t){
      int j = (t << 6) + lane;
      float4 q = spts[j];
      float d = 2.f*(pi.x*q.x + pi.y*q.y + pi.z*q.z) - pi.w - q.w;  // neg sq dist
      if (d > b1){ b3=b2; i3=i2; b2=b1; i2=i1; b1=d; i1=j; }
      else if (d > b2){ b3=b2; i3=i2; b2=d; i2=j; }
      else if (d > b3){ b3=d; i3=j; }
    }
    unsigned long long rem = 0ull;        // removed candidate t-bits (per lane)
    size_t obase = ((size_t)b*NPTS + i)*KNB;
    #pragma unroll 1
    for (int kk = 0; kk < KNB; ++kk){
      float bv = b1; int bi = i1;
      #pragma unroll
      for (int m = 32; m > 0; m >>= 1){      // argmax, smallest-index tie-break
        float ov = __shfl_xor(bv, m);
        int   oi = __shfl_xor(bi, m);
        if (ov > bv || (ov == bv && oi < bi)){ bv = ov; bi = oi; }
      }
      if (lane == 0) idx_out[obase + kk] = bi;
      if ((bi & 63) == lane){                // this lane's best won: remove+promote
        rem |= 1ull << (bi >> 6);
        b1 = b2; i1 = i2; b2 = b3; i2 = i3; b3 = -INFINITY; i3 = 0;
        if (b1 == -INFINITY){                // rare: rebuild top-3 from LDS
          #pragma unroll 8
          for (int t = 0; t < 64; ++t){
            if (rem & (1ull << t)) continue;
            int j = (t << 6) + lane;
            float4 q = spts[j];
            float d = 2.f*(pi.x*q.x + pi.y*q.y + pi.z*q.z) - pi.w - q.w;
            if (d > b1){ b3=b2; i3=i2; b2=b1; i2=i1; b1=d; i1=j; }
            else if (d > b2){ b3=b2; i3=i2; b2=d; i2=j; }
            else if (d > b3){ b3=d; i3=j; }
          }
        }
      }
    }
  }
}

// ---------------- weight prep: fp32 [K][O] -> fp16 [O][K] ----------------
__global__ __launch_bounds__(256)
void prep_kernel(const float* __restrict__ W2, const float* __restrict__ W3,
                 const float* __restrict__ W4, const float* __restrict__ W5,
                 _Float16* __restrict__ W2T, _Float16* __restrict__ W3T,
                 _Float16* __restrict__ W4T, _Float16* __restrict__ W5T){
  int t = blockIdx.x*256 + threadIdx.x;
  if (t < 4096){ int o=t>>6, k=t&63;                W2T[t] = (_Float16)W2[k*64+o]; }
  else if (t < 12288){ int u=t-4096;  int o=u>>6, k=u&63;   W3T[u] = (_Float16)W3[k*128+o]; }
  else if (t < 45056){ int u=t-12288; int o=u>>7, k=u&127;  W4T[u] = (_Float16)W4[k*256+o]; }
  else if (t < 569344){ int u=t-45056; int o=u>>9, k=u&511; W5T[u] = (_Float16)W5[k*1024+o]; }
}

// ---------------- fused edge layers 1-4 ----------------
__global__ __launch_bounds__(256)
void edge_kernel(const float* __restrict__ x, const int* __restrict__ knn,
                 const float* __restrict__ W1, const float* __restrict__ g1, const float* __restrict__ b1,
                 const _Float16* __restrict__ W2T, const float* __restrict__ g2, const float* __restrict__ b2,
                 const _Float16* __restrict__ W3T, const float* __restrict__ g3, const float* __restrict__ b3,
                 const _Float16* __restrict__ W4T, const float* __restrict__ g4, const float* __restrict__ b4,
                 _Float16* __restrict__ hc){
  __shared__ float h0[80][8];
  __shared__ __align__(16) _Float16 hb1[80*64];
  __shared__ __align__(16) _Float16 hb2[80*64];
  __shared__ __align__(16) _Float16 hb3[80*128];
  const float rs = 1.f / sqrtf(1.f + EPSB);
  int gp0 = blockIdx.x << 2;              // 4 points per block
  int b   = gp0 >> 12;
  int n0  = gp0 & (NPTS-1);
  const float* xb = x + (size_t)b*NPTS*3;
  if (threadIdx.x < 80){
    int p = threadIdx.x / 20, k = threadIdx.x % 20;
    int n = n0 + p;
    int nb = knn[((size_t)b*NPTS + n)*KNB + k];
    h0[threadIdx.x][0] = xb[nb*3+0];
    h0[threadIdx.x][1] = xb[nb*3+1];
    h0[threadIdx.x][2] = xb[nb*3+2];
    h0[threadIdx.x][3] = xb[n*3+0];
    h0[threadIdx.x][4] = xb[n*3+1];
    h0[threadIdx.x][5] = xb[n*3+2];
  }
  __syncthreads();
  int wave = threadIdx.x >> 6, lane = threadIdx.x & 63;
  // layer 1: [80,6]@[6,64], fp32 VALU
  {
    int col = threadIdx.x & 63;
    float sc = g1[col]*rs, bs = b1[col];
    float w0=W1[col], w1=W1[64+col], w2=W1[128+col], w3=W1[192+col], w4=W1[256+col], w5=W1[320+col];
    #pragma unroll 1
    for (int r = threadIdx.x >> 6; r < 80; r += 4){
      float a = h0[r][0]*w0 + h0[r][1]*w1 + h0[r][2]*w2 + h0[r][3]*w3 + h0[r][4]*w4 + h0[r][5]*w5;
      float vv = a*sc + bs; vv = vv>0.f ? vv : 0.2f*vv;
      hb1[((r<<6)+col) ^ ((r&7)<<3)] = (_Float16)vv;
    }
  }
  __syncthreads();
  // layer 2: [80,64]@[64,64] — wave owns N-tile `wave`
  {
    int nt = wave;
    int col = (nt<<4) + (lane&15);
    float sc = g2[col]*rs, bs = b2[col];
    half8 bf0 = loadB_g(W2T, 64, nt, 0, lane);
    half8 bf1 = loadB_g(W2T, 64, nt, 1, lane);
    #pragma unroll
    for (int mt = 0; mt < 5; ++mt){
      f32x4 acc = {0.f,0.f,0.f,0.f};
      acc = mfma16(loadA_lds(hb1,64,mt,0,lane), bf0, acc);
      acc = mfma16(loadA_lds(hb1,64,mt,1,lane), bf1, acc);
      storeTile(hb2, 64, mt, nt, lane, acc, sc, bs);
    }
  }
  __syncthreads();
  // layer 3: [80,64]@[64,128] — wave owns N-tiles 2w,2w+1
  {
    #pragma unroll
    for (int tt = 0; tt < 2; ++tt){
      int nt = (wave<<1) + tt;
      int col = (nt<<4) + (lane&15);
      float sc = g3[col]*rs, bs = b3[col];
      half8 bf0 = loadB_g(W3T, 64, nt, 0, lane);
      half8 bf1 = loadB_g(W3T, 64, nt, 1, lane);
      #pragma unroll
      for (int mt = 0; mt < 5; ++mt){
        f32x4 acc = {0.f,0.f,0.f,0.f};
        acc = mfma16(loadA_lds(hb2,64,mt,0,lane), bf0, acc);
        acc = mfma16(loadA_lds(hb2,64,mt,1,lane), bf1, acc);
        storeTile(hb3, 128, mt, nt, lane, acc, sc, bs);
      }
    }
  }
  __syncthreads();
  // max-over-K epilogues for x1,x2,x3
  {
    int p = threadIdx.x >> 6, c = threadIdx.x & 63;
    float m1=-INFINITY, m2=-INFINITY, m3a=-INFINITY, m3b=-INFINITY;
    #pragma unroll 1
    for (int k = 0; k < KNB; ++k){
      int r = p*20 + k;
      m1  = fmaxf(m1,  hval(hb1, 64,  r, c));
      m2  = fmaxf(m2,  hval(hb2, 64,  r, c));
      m3a = fmaxf(m3a, hval(hb3, 128, r, c));
      m3b = fmaxf(m3b, hval(hb3, 128, r, c+64));
    }
    size_t o = (size_t)(gp0 + p) * 512;
    hc[o + c]        = (_Float16)m1;
    hc[o + 64  + c]  = (_Float16)m2;
    hc[o + 128 + c]  = (_Float16)m3a;
    hc[o + 192 + c]  = (_Float16)m3b;
  }
  __syncthreads();
  // layer 4: [80,128]@[128,256] in 4 chunks of 64 cols (hb1 reused as chunk buf)
  #pragma unroll 1
  for (int ch = 0; ch < 4; ++ch){
    {
      int ntg = (ch<<2) + wave;
      int col = (ntg<<4) + (lane&15);
      float sc = g4[col]*rs, bs = b4[col];
      half8 bw[4];
      #pragma unroll
      for (int ks = 0; ks < 4; ++ks) bw[ks] = loadB_g(W4T, 128, ntg, ks, lane);
      #pragma unroll
      for (int mt = 0; mt < 5; ++mt){
        f32x4 acc = {0.f,0.f,0.f,0.f};
        #pragma unroll
        for (int ks = 0; ks < 4; ++ks)
          acc = mfma16(loadA_lds(hb3,128,mt,ks,lane), bw[ks], acc);
        storeTile(hb1, 64, mt, wave, lane, acc, sc, bs);
      }
    }
    __syncthreads();
    {
      int p = threadIdx.x >> 6, c = threadIdx.x & 63;
      float m = -INFINITY;
      #pragma unroll 1
      for (int k = 0; k < KNB; ++k)
        m = fmaxf(m, hval(hb1, 64, p*20 + k, c));
      hc[(size_t)(gp0 + p)*512 + 256 + (ch<<6) + c] = (_Float16)m;
    }
    __syncthreads();
  }
}

// ---------------- layer 5 GEMM + pooling partials ----------------
__global__ __launch_bounds__(256)
void gemm5_kernel(const _Float16* __restrict__ hc, const _Float16* __restrict__ W5T,
                  const float* __restrict__ g5, const float* __restrict__ b5,
                  float* __restrict__ red){
  __shared__ __align__(16) _Float16 sA[64*512];   // 64KB
  int rowblk = blockIdx.x >> 2;
  int colblk = blockIdx.x & 3;
  int row0 = rowblk << 6;
  // stage A chunk: swizzled source -> linear LDS (so swizzled reads see hc[row][k])
  #pragma unroll 1
  for (int it = 0; it < 16; ++it){
    int eoff = it*2048 + threadIdx.x*8;
    int row = eoff >> 9;
    int ine = eoff & 511;
    half8 vsrc = *reinterpret_cast<const half8*>(
        &hc[(size_t)(row0 + row)*512 + (ine ^ ((row & 7) << 3))]);
    *reinterpret_cast<half8*>(&sA[(row << 9) + ine]) = vsrc;
  }
  __syncthreads();
  int wave = threadIdx.x >> 6, lane = threadIdx.x & 63;
  f32x4 acc[4][4] = {};
  #pragma unroll 1
  for (int ks = 0; ks < 16; ++ks){
    half8 af[4];
    #pragma unroll
    for (int mt = 0; mt < 4; ++mt) af[mt] = loadA_lds(sA, 512, mt, ks, lane);
    #pragma unroll
    for (int nt = 0; nt < 4; ++nt){
      int ntg = (colblk<<4) + (wave<<2) + nt;
      half8 bf = loadB_g(W5T, 512, ntg, ks, lane);
      #pragma unroll
      for (int mt = 0; mt < 4; ++mt)
        acc[mt][nt] = mfma16(af[mt], bf, acc[mt][nt]);
    }
  }
  int batch = row0 >> 12;
  int chunk = (row0 & (NPTS-1)) >> 6;
  const float rs = 1.f/sqrtf(1.f+EPSB);
  #pragma unroll
  for (int nt = 0; nt < 4; ++nt){
    int ntg = (colblk<<4) + (wave<<2) + nt;
    int colg = (ntg<<4) + (lane & 15);
    float sc = g5[colg]*rs, bs = b5[colg];
    float vmax = -INFINITY, vsum = 0.f;
    #pragma unroll
    for (int mt = 0; mt < 4; ++mt){
      #pragma unroll
      for (int r = 0; r < 4; ++r){
        float vv = acc[mt][nt][r]*sc + bs;
        vv = vv>0.f ? vv : 0.2f*vv;
        vmax = fmaxf(vmax, vv); vsum += vv;
      }
    }
    vmax = fmaxf(vmax, __shfl_xor(vmax, 16)); vsum += __shfl_xor(vsum, 16);
    vmax = fmaxf(vmax, __shfl_xor(vmax, 32)); vsum += __shfl_xor(vsum, 32);
    if ((lane >> 4) == 0){
      size_t base = (size_t)((batch<<6) + chunk)*2048;
      red[base + colg] = vmax;
      red[base + 1024 + colg] = vsum;
    }
  }
}

__global__ __launch_bounds__(256)
void reduce_g_kernel(const float* __restrict__ red, float* __restrict__ g){
  int t = blockIdx.x*256 + threadIdx.x;   // 8192
  int b = t >> 10, col = t & 1023;
  float m = -INFINITY, s = 0.f;
  #pragma unroll 4
  for (int c = 0; c < 64; ++c){
    size_t base = (size_t)((b<<6)+c)*2048;
    m = fmaxf(m, red[base + col]);
    s += red[base + 1024 + col];
  }
  g[(b<<11) + col]        = m;
  g[(b<<11) + 1024 + col] = s * (1.f/4096.f);
}

// ---------------- head MLP ----------------
__global__ __launch_bounds__(256)
void fc1_kernel(const float* __restrict__ g, const float* __restrict__ L1,
                const float* __restrict__ g6, const float* __restrict__ b6,
                float* __restrict__ f1){
  int t = blockIdx.x*256 + threadIdx.x;   // 4096
  int b = t >> 9, o = t & 511;
  const float* gb = g + (b<<11);
  float acc = 0.f;
  #pragma unroll 8
  for (int c = 0; c < 2048; ++c) acc += gb[c]*L1[c*512 + o];
  float v = acc*(g6[o]/sqrtf(1.f+EPSB)) + b6[o];
  f1[t] = v>0.f ? v : 0.2f*v;
}

__global__ __launch_bounds__(256)
void fc2_kernel(const float* __restrict__ f1, const float* __restrict__ L2, const float* __restrict__ L2b,
                const float* __restrict__ g7, const float* __restrict__ b7, float* __restrict__ f2){
  int t = blockIdx.x*256 + threadIdx.x;   // 2048
  int b = t >> 8, o = t & 255;
  const float* fb = f1 + (b<<9);
  float acc = 0.f;
  #pragma unroll 8
  for (int c = 0; c < 512; ++c) acc += fb[c]*L2[c*256 + o];
  float v = (acc + L2b[o])*(g7[o]/sqrtf(1.f+EPSB)) + b7[o];
  f2[t] = v>0.f ? v : 0.2f*v;
}

__global__ __launch_bounds__(256)
void fc3_kernel(const float* __restrict__ f2, const float* __restrict__ L3, const float* __restrict__ L3b,
                float* __restrict__ out){
  int t = blockIdx.x*256 + threadIdx.x;   // 1024
  int b = t >> 7, o = t & 127;
  const float* fb = f2 + (b<<8);
  float acc = 0.f;
  #pragma unroll 8
  for (int c = 0; c < 256; ++c) acc += fb[c]*L3[c*128 + o];
  out[t] = acc + L3b[o];
}

extern "C" void kernel_launch(void* const* d_in, const int* in_sizes, int n_in,
                              void* d_out, int out_size, void* d_ws, size_t ws_size,
                              hipStream_t stream){
  const float* x  = (const float*)d_in[0];
  const float* W1 = (const float*)d_in[1];
  const float* g1 = (const float*)d_in[2];  const float* b1 = (const float*)d_in[3];
  const float* W2 = (const float*)d_in[4];
  const float* g2 = (const float*)d_in[5];  const float* b2 = (const float*)d_in[6];
  const float* W3 = (const float*)d_in[7];
  const float* g3 = (const float*)d_in[8];  const float* b3 = (const float*)d_in[9];
  const float* W4 = (const float*)d_in[10];
  const float* g4 = (const float*)d_in[11]; const float* b4 = (const float*)d_in[12];
  const float* W5 = (const float*)d_in[13];
  const float* g5 = (const float*)d_in[14]; const float* b5 = (const float*)d_in[15];
  const float* L1 = (const float*)d_in[16];
  const float* g6 = (const float*)d_in[17]; const float* b6 = (const float*)d_in[18];
  const float* L2 = (const float*)d_in[19]; const float* L2b = (const float*)d_in[20];
  const float* g7 = (const float*)d_in[21]; const float* b7 = (const float*)d_in[22];
  const float* L3 = (const float*)d_in[23]; const float* L3b = (const float*)d_in[24];

  char* ws = (char*)d_ws;
  int*      idx  = (int*)(ws + 0);                 // 2,621,440 B
  _Float16* hc   = (_Float16*)(ws + 2621440);      // 33,554,432 B
  _Float16* W2T  = (_Float16*)(ws + 36175872);     // 8,192 B
  _Float16* W3T  = (_Float16*)(ws + 36184064);     // 16,384 B
  _Float16* W4T  = (_Float16*)(ws + 36200448);     // 65,536 B
  _Float16* W5T  = (_Float16*)(ws + 36265984);     // 1,048,576 B
  float*    red  = (float*)(ws + 37314560);        // 4,194,304 B
  float*    gbuf = (float*)(ws + 41508864);        // 65,536 B
  float*    f1   = (float*)(ws + 41574400);        // 16,384 B
  float*    f2   = (float*)(ws + 41590784);        // 8,192 B

  knn_kernel<<<2048, 512, 0, stream>>>(x, idx);
  prep_kernel<<<2224, 256, 0, stream>>>(W2, W3, W4, W5, W2T, W3T, W4T, W5T);
  edge_kernel<<<8192, 256, 0, stream>>>(x, idx, W1, g1, b1, W2T, g2, b2,
                                        W3T, g3, b3, W4T, g4, b4, hc);
  gemm5_kernel<<<2048, 256, 0, stream>>>(hc, W5T, g5, b5, red);
  reduce_g_kernel<<<32, 256, 0, stream>>>(red, gbuf);
  fc1_kernel<<<16, 256, 0, stream>>>(gbuf, L1, g6, b6, f1);
  fc2_kernel<<<8, 256, 0, stream>>>(f1, L2, L2b, g7, b7, f2);
  fc3_kernel<<<4, 256, 0, stream>>>(f2, L3, L3b, (float*)d_out);
}

// Round 4
// 658.686 us; speedup vs baseline: 2.4578x; 1.1547x over previous
//
#include <hip/hip_runtime.h>
#include <hip/hip_bf16.h>
#include <hip/hip_fp16.h>

#define NPTS 4096
#define KNB  20
#define EPSB 1e-5f

typedef _Float16 half8 __attribute__((ext_vector_type(8)));
typedef float    f32x4 __attribute__((ext_vector_type(4)));

__device__ __forceinline__ f32x4 mfma16(half8 a, half8 b, f32x4 c){
  return __builtin_amdgcn_mfma_f32_16x16x32_f16(a, b, c, 0, 0, 0);
}

// A fragment from LDS, row-major [rows][C] fp16, XOR-swizzled by (row&7)<<3 elements.
__device__ __forceinline__ half8 loadA_lds(const _Float16* buf, int C, int mt, int ks, int lane){
  int row = mt*16 + (lane & 15);
  int k0  = ks*32 + (lane >> 4)*8;
  int e   = (row*C + k0) ^ ((row & 7) << 3);
  return *reinterpret_cast<const half8*>(&buf[e]);
}

// B fragment from global, WT is [N_out][K] fp16 (pre-transposed weight)
__device__ __forceinline__ half8 loadB_g(const _Float16* WT, int K, int nt, int ks, int lane){
  int col = nt*16 + (lane & 15);
  int k0  = ks*32 + (lane >> 4)*8;
  return *reinterpret_cast<const half8*>(&WT[col*K + k0]);
}

// C/D layout (verified m89): col = lane&15, row = (lane>>4)*4 + r
__device__ __forceinline__ void storeTile(_Float16* buf, int C, int mt, int nt, int lane,
                                          f32x4 acc, float sc, float bs){
  int col = nt*16 + (lane & 15);
  #pragma unroll
  for (int r = 0; r < 4; ++r){
    int row = mt*16 + (lane >> 4)*4 + r;
    float v = acc[r]*sc + bs;
    v = v > 0.f ? v : 0.2f*v;
    buf[(row*C + col) ^ ((row & 7) << 3)] = (_Float16)v;
  }
}

__device__ __forceinline__ float hval(const _Float16* buf, int C, int r, int c){
  return (float)buf[(r*C + c) ^ ((r & 7) << 3)];
}

// ---------------- KNN ----------------
// 1024 threads = 16 waves, ONE row per wave (full occupancy, shortest serial chain).
// Per lane: candidates j = t*64+lane, t=0..63, distances streamed from LDS (no
// per-lane array -> no scratch). Per-lane top-3 cache; butterfly argmax per
// neighbor; winner promotes cache, rebuilds from LDS only when exhausted.
__global__ __launch_bounds__(1024)
void knn_kernel(const float* __restrict__ x, int* __restrict__ idx_out){
  __shared__ float4 spts[NPTS];           // (x,y,z,xx) 64KB
  int b  = blockIdx.x >> 8;               // 256 row-blocks per batch
  int r0 = (blockIdx.x & 255) << 4;       // 16 rows per block
  const float* xb = x + (size_t)b*NPTS*3;
  for (int t = threadIdx.x; t < NPTS; t += 1024){
    float px = xb[t*3+0], py = xb[t*3+1], pz = xb[t*3+2];
    spts[t] = make_float4(px, py, pz, px*px + py*py + pz*pz);
  }
  __syncthreads();
  int wave = threadIdx.x >> 6, lane = threadIdx.x & 63;
  int i = r0 + wave;
  float4 pi = spts[i];
  float b1 = -INFINITY, b2 = -INFINITY, b3 = -INFINITY;
  int   i1 = 0, i2 = 0, i3 = 0;
  #pragma unroll 8
  for (int t = 0; t < 64; ++t){
    int j = (t << 6) + lane;
    float4 q = spts[j];
    float d = 2.f*(pi.x*q.x + pi.y*q.y + pi.z*q.z) - pi.w - q.w;  // neg sq dist
    if (d > b1){ b3=b2; i3=i2; b2=b1; i2=i1; b1=d; i1=j; }
    else if (d > b2){ b3=b2; i3=i2; b2=d; i2=j; }
    else if (d > b3){ b3=d; i3=j; }
  }
  unsigned long long rem = 0ull;          // removed candidate t-bits (per lane)
  size_t obase = ((size_t)b*NPTS + i)*KNB;
  #pragma unroll 1
  for (int kk = 0; kk < KNB; ++kk){
    float bv = b1; int bi = i1;
    #pragma unroll
    for (int m = 32; m > 0; m >>= 1){      // argmax, smallest-index tie-break
      float ov = __shfl_xor(bv, m);
      int   oi = __shfl_xor(bi, m);
      if (ov > bv || (ov == bv && oi < bi)){ bv = ov; bi = oi; }
    }
    if (lane == 0) idx_out[obase + kk] = bi;
    if ((bi & 63) == lane){                // this lane's best won: remove+promote
      rem |= 1ull << (bi >> 6);
      b1 = b2; i1 = i2; b2 = b3; i2 = i3; b3 = -INFINITY; i3 = 0;
      if (b1 == -INFINITY){                // rare: rebuild top-3 from LDS
        #pragma unroll 8
        for (int t = 0; t < 64; ++t){
          if (rem & (1ull << t)) continue;
          int j = (t << 6) + lane;
          float4 q = spts[j];
          float d = 2.f*(pi.x*q.x + pi.y*q.y + pi.z*q.z) - pi.w - q.w;
          if (d > b1){ b3=b2; i3=i2; b2=b1; i2=i1; b1=d; i1=j; }
          else if (d > b2){ b3=b2; i3=i2; b2=d; i2=j; }
          else if (d > b3){ b3=d; i3=j; }
        }
      }
    }
  }
}

// ---------------- weight prep: fp32 [K][O] -> fp16 [O][K] ----------------
__global__ __launch_bounds__(256)
void prep_kernel(const float* __restrict__ W2, const float* __restrict__ W3,
                 const float* __restrict__ W4, const float* __restrict__ W5,
                 _Float16* __restrict__ W2T, _Float16* __restrict__ W3T,
                 _Float16* __restrict__ W4T, _Float16* __restrict__ W5T){
  int t = blockIdx.x*256 + threadIdx.x;
  if (t < 4096){ int o=t>>6, k=t&63;                W2T[t] = (_Float16)W2[k*64+o]; }
  else if (t < 12288){ int u=t-4096;  int o=u>>6, k=u&63;   W3T[u] = (_Float16)W3[k*128+o]; }
  else if (t < 45056){ int u=t-12288; int o=u>>7, k=u&127;  W4T[u] = (_Float16)W4[k*256+o]; }
  else if (t < 569344){ int u=t-45056; int o=u>>9, k=u&511; W5T[u] = (_Float16)W5[k*1024+o]; }
}

// ---------------- fused edge layers 1-4 ----------------
__global__ __launch_bounds__(256)
void edge_kernel(const float* __restrict__ x, const int* __restrict__ knn,
                 const float* __restrict__ W1, const float* __restrict__ g1, const float* __restrict__ b1,
                 const _Float16* __restrict__ W2T, const float* __restrict__ g2, const float* __restrict__ b2,
                 const _Float16* __restrict__ W3T, const float* __restrict__ g3, const float* __restrict__ b3,
                 const _Float16* __restrict__ W4T, const float* __restrict__ g4, const float* __restrict__ b4,
                 _Float16* __restrict__ hc){
  __shared__ float h0[80][8];
  __shared__ __align__(16) _Float16 hb1[80*64];
  __shared__ __align__(16) _Float16 hb2[80*64];
  __shared__ __align__(16) _Float16 hb3[80*128];
  const float rs = 1.f / sqrtf(1.f + EPSB);
  int gp0 = blockIdx.x << 2;              // 4 points per block
  int b   = gp0 >> 12;
  int n0  = gp0 & (NPTS-1);
  const float* xb = x + (size_t)b*NPTS*3;
  if (threadIdx.x < 80){
    int p = threadIdx.x / 20, k = threadIdx.x % 20;
    int n = n0 + p;
    int nb = knn[((size_t)b*NPTS + n)*KNB + k];
    h0[threadIdx.x][0] = xb[nb*3+0];
    h0[threadIdx.x][1] = xb[nb*3+1];
    h0[threadIdx.x][2] = xb[nb*3+2];
    h0[threadIdx.x][3] = xb[n*3+0];
    h0[threadIdx.x][4] = xb[n*3+1];
    h0[threadIdx.x][5] = xb[n*3+2];
  }
  __syncthreads();
  int wave = threadIdx.x >> 6, lane = threadIdx.x & 63;
  // layer 1: [80,6]@[6,64], fp32 VALU
  {
    int col = threadIdx.x & 63;
    float sc = g1[col]*rs, bs = b1[col];
    float w0=W1[col], w1=W1[64+col], w2=W1[128+col], w3=W1[192+col], w4=W1[256+col], w5=W1[320+col];
    #pragma unroll 1
    for (int r = threadIdx.x >> 6; r < 80; r += 4){
      float a = h0[r][0]*w0 + h0[r][1]*w1 + h0[r][2]*w2 + h0[r][3]*w3 + h0[r][4]*w4 + h0[r][5]*w5;
      float vv = a*sc + bs; vv = vv>0.f ? vv : 0.2f*vv;
      hb1[((r<<6)+col) ^ ((r&7)<<3)] = (_Float16)vv;
    }
  }
  __syncthreads();
  // layer 2: [80,64]@[64,64] — wave owns N-tile `wave`
  {
    int nt = wave;
    int col = (nt<<4) + (lane&15);
    float sc = g2[col]*rs, bs = b2[col];
    half8 bf0 = loadB_g(W2T, 64, nt, 0, lane);
    half8 bf1 = loadB_g(W2T, 64, nt, 1, lane);
    #pragma unroll
    for (int mt = 0; mt < 5; ++mt){
      f32x4 acc = {0.f,0.f,0.f,0.f};
      acc = mfma16(loadA_lds(hb1,64,mt,0,lane), bf0, acc);
      acc = mfma16(loadA_lds(hb1,64,mt,1,lane), bf1, acc);
      storeTile(hb2, 64, mt, nt, lane, acc, sc, bs);
    }
  }
  __syncthreads();
  // layer 3: [80,64]@[64,128] — wave owns N-tiles 2w,2w+1
  {
    #pragma unroll
    for (int tt = 0; tt < 2; ++tt){
      int nt = (wave<<1) + tt;
      int col = (nt<<4) + (lane&15);
      float sc = g3[col]*rs, bs = b3[col];
      half8 bf0 = loadB_g(W3T, 64, nt, 0, lane);
      half8 bf1 = loadB_g(W3T, 64, nt, 1, lane);
      #pragma unroll
      for (int mt = 0; mt < 5; ++mt){
        f32x4 acc = {0.f,0.f,0.f,0.f};
        acc = mfma16(loadA_lds(hb2,64,mt,0,lane), bf0, acc);
        acc = mfma16(loadA_lds(hb2,64,mt,1,lane), bf1, acc);
        storeTile(hb3, 128, mt, nt, lane, acc, sc, bs);
      }
    }
  }
  __syncthreads();
  // max-over-K epilogues for x1,x2,x3
  {
    int p = threadIdx.x >> 6, c = threadIdx.x & 63;
    float m1=-INFINITY, m2=-INFINITY, m3a=-INFINITY, m3b=-INFINITY;
    #pragma unroll 1
    for (int k = 0; k < KNB; ++k){
      int r = p*20 + k;
      m1  = fmaxf(m1,  hval(hb1, 64,  r, c));
      m2  = fmaxf(m2,  hval(hb2, 64,  r, c));
      m3a = fmaxf(m3a, hval(hb3, 128, r, c));
      m3b = fmaxf(m3b, hval(hb3, 128, r, c+64));
    }
    size_t o = (size_t)(gp0 + p) * 512;
    hc[o + c]        = (_Float16)m1;
    hc[o + 64  + c]  = (_Float16)m2;
    hc[o + 128 + c]  = (_Float16)m3a;
    hc[o + 192 + c]  = (_Float16)m3b;
  }
  __syncthreads();
  // layer 4: [80,128]@[128,256] in 4 chunks of 64 cols (hb1 reused as chunk buf)
  #pragma unroll 1
  for (int ch = 0; ch < 4; ++ch){
    {
      int ntg = (ch<<2) + wave;
      int col = (ntg<<4) + (lane&15);
      float sc = g4[col]*rs, bs = b4[col];
      half8 bw[4];
      #pragma unroll
      for (int ks = 0; ks < 4; ++ks) bw[ks] = loadB_g(W4T, 128, ntg, ks, lane);
      #pragma unroll
      for (int mt = 0; mt < 5; ++mt){
        f32x4 acc = {0.f,0.f,0.f,0.f};
        #pragma unroll
        for (int ks = 0; ks < 4; ++ks)
          acc = mfma16(loadA_lds(hb3,128,mt,ks,lane), bw[ks], acc);
        storeTile(hb1, 64, mt, wave, lane, acc, sc, bs);
      }
    }
    __syncthreads();
    {
      int p = threadIdx.x >> 6, c = threadIdx.x & 63;
      float m = -INFINITY;
      #pragma unroll 1
      for (int k = 0; k < KNB; ++k)
        m = fmaxf(m, hval(hb1, 64, p*20 + k, c));
      hc[(size_t)(gp0 + p)*512 + 256 + (ch<<6) + c] = (_Float16)m;
    }
    __syncthreads();
  }
}

// ---------------- layer 5 GEMM + pooling partials ----------------
__global__ __launch_bounds__(256)
void gemm5_kernel(const _Float16* __restrict__ hc, const _Float16* __restrict__ W5T,
                  const float* __restrict__ g5, const float* __restrict__ b5,
                  float* __restrict__ red){
  __shared__ __align__(16) _Float16 sA[64*512];   // 64KB
  int rowblk = blockIdx.x >> 2;
  int colblk = blockIdx.x & 3;
  int row0 = rowblk << 6;
  // stage A chunk: swizzled source -> linear LDS (so swizzled reads see hc[row][k])
  #pragma unroll 1
  for (int it = 0; it < 16; ++it){
    int eoff = it*2048 + threadIdx.x*8;
    int row = eoff >> 9;
    int ine = eoff & 511;
    half8 vsrc = *reinterpret_cast<const half8*>(
        &hc[(size_t)(row0 + row)*512 + (ine ^ ((row & 7) << 3))]);
    *reinterpret_cast<half8*>(&sA[(row << 9) + ine]) = vsrc;
  }
  __syncthreads();
  int wave = threadIdx.x >> 6, lane = threadIdx.x & 63;
  f32x4 acc[4][4] = {};
  #pragma unroll 1
  for (int ks = 0; ks < 16; ++ks){
    half8 af[4];
    #pragma unroll
    for (int mt = 0; mt < 4; ++mt) af[mt] = loadA_lds(sA, 512, mt, ks, lane);
    #pragma unroll
    for (int nt = 0; nt < 4; ++nt){
      int ntg = (colblk<<4) + (wave<<2) + nt;
      half8 bf = loadB_g(W5T, 512, ntg, ks, lane);
      #pragma unroll
      for (int mt = 0; mt < 4; ++mt)
        acc[mt][nt] = mfma16(af[mt], bf, acc[mt][nt]);
    }
  }
  int batch = row0 >> 12;
  int chunk = (row0 & (NPTS-1)) >> 6;
  const float rs = 1.f/sqrtf(1.f+EPSB);
  #pragma unroll
  for (int nt = 0; nt < 4; ++nt){
    int ntg = (colblk<<4) + (wave<<2) + nt;
    int colg = (ntg<<4) + (lane & 15);
    float sc = g5[colg]*rs, bs = b5[colg];
    float vmax = -INFINITY, vsum = 0.f;
    #pragma unroll
    for (int mt = 0; mt < 4; ++mt){
      #pragma unroll
      for (int r = 0; r < 4; ++r){
        float vv = acc[mt][nt][r]*sc + bs;
        vv = vv>0.f ? vv : 0.2f*vv;
        vmax = fmaxf(vmax, vv); vsum += vv;
      }
    }
    vmax = fmaxf(vmax, __shfl_xor(vmax, 16)); vsum += __shfl_xor(vsum, 16);
    vmax = fmaxf(vmax, __shfl_xor(vmax, 32)); vsum += __shfl_xor(vsum, 32);
    if ((lane >> 4) == 0){
      size_t base = (size_t)((batch<<6) + chunk)*2048;
      red[base + colg] = vmax;
      red[base + 1024 + colg] = vsum;
    }
  }
}

__global__ __launch_bounds__(256)
void reduce_g_kernel(const float* __restrict__ red, float* __restrict__ g){
  int t = blockIdx.x*256 + threadIdx.x;   // 8192
  int b = t >> 10, col = t & 1023;
  float m = -INFINITY, s = 0.f;
  #pragma unroll 4
  for (int c = 0; c < 64; ++c){
    size_t base = (size_t)((b<<6)+c)*2048;
    m = fmaxf(m, red[base + col]);
    s += red[base + 1024 + col];
  }
  g[(b<<11) + col]        = m;
  g[(b<<11) + 1024 + col] = s * (1.f/4096.f);
}

// ---------------- head MLP ----------------
__global__ __launch_bounds__(256)
void fc1_kernel(const float* __restrict__ g, const float* __restrict__ L1,
                const float* __restrict__ g6, const float* __restrict__ b6,
                float* __restrict__ f1){
  int t = blockIdx.x*256 + threadIdx.x;   // 4096
  int b = t >> 9, o = t & 511;
  const float* gb = g + (b<<11);
  float acc = 0.f;
  #pragma unroll 8
  for (int c = 0; c < 2048; ++c) acc += gb[c]*L1[c*512 + o];
  float v = acc*(g6[o]/sqrtf(1.f+EPSB)) + b6[o];
  f1[t] = v>0.f ? v : 0.2f*v;
}

__global__ __launch_bounds__(256)
void fc2_kernel(const float* __restrict__ f1, const float* __restrict__ L2, const float* __restrict__ L2b,
                const float* __restrict__ g7, const float* __restrict__ b7, float* __restrict__ f2){
  int t = blockIdx.x*256 + threadIdx.x;   // 2048
  int b = t >> 8, o = t & 255;
  const float* fb = f1 + (b<<9);
  float acc = 0.f;
  #pragma unroll 8
  for (int c = 0; c < 512; ++c) acc += fb[c]*L2[c*256 + o];
  float v = (acc + L2b[o])*(g7[o]/sqrtf(1.f+EPSB)) + b7[o];
  f2[t] = v>0.f ? v : 0.2f*v;
}

__global__ __launch_bounds__(256)
void fc3_kernel(const float* __restrict__ f2, const float* __restrict__ L3, const float* __restrict__ L3b,
                float* __restrict__ out){
  int t = blockIdx.x*256 + threadIdx.x;   // 1024
  int b = t >> 7, o = t & 127;
  const float* fb = f2 + (b<<8);
  float acc = 0.f;
  #pragma unroll 8
  for (int c = 0; c < 256; ++c) acc += fb[c]*L3[c*128 + o];
  out[t] = acc + L3b[o];
}

extern "C" void kernel_launch(void* const* d_in, const int* in_sizes, int n_in,
                              void* d_out, int out_size, void* d_ws, size_t ws_size,
                              hipStream_t stream){
  const float* x  = (const float*)d_in[0];
  const float* W1 = (const float*)d_in[1];
  const float* g1 = (const float*)d_in[2];  const float* b1 = (const float*)d_in[3];
  const float* W2 = (const float*)d_in[4];
  const float* g2 = (const float*)d_in[5];  const float* b2 = (const float*)d_in[6];
  const float* W3 = (const float*)d_in[7];
  const float* g3 = (const float*)d_in[8];  const float* b3 = (const float*)d_in[9];
  const float* W4 = (const float*)d_in[10];
  const float* g4 = (const float*)d_in[11]; const float* b4 = (const float*)d_in[12];
  const float* W5 = (const float*)d_in[13];
  const float* g5 = (const float*)d_in[14]; const float* b5 = (const float*)d_in[15];
  const float* L1 = (const float*)d_in[16];
  const float* g6 = (const float*)d_in[17]; const float* b6 = (const float*)d_in[18];
  const float* L2 = (const float*)d_in[19]; const float* L2b = (const float*)d_in[20];
  const float* g7 = (const float*)d_in[21]; const float* b7 = (const float*)d_in[22];
  const float* L3 = (const float*)d_in[23]; const float* L3b = (const float*)d_in[24];

  char* ws = (char*)d_ws;
  int*      idx  = (int*)(ws + 0);                 // 2,621,440 B
  _Float16* hc   = (_Float16*)(ws + 2621440);      // 33,554,432 B
  _Float16* W2T  = (_Float16*)(ws + 36175872);     // 8,192 B
  _Float16* W3T  = (_Float16*)(ws + 36184064);     // 16,384 B
  _Float16* W4T  = (_Float16*)(ws + 36200448);     // 65,536 B
  _Float16* W5T  = (_Float16*)(ws + 36265984);     // 1,048,576 B
  float*    red  = (float*)(ws + 37314560);        // 4,194,304 B
  float*    gbuf = (float*)(ws + 41508864);        // 65,536 B
  float*    f1   = (float*)(ws + 41574400);        // 16,384 B
  float*    f2   = (float*)(ws + 41590784);        // 8,192 B

  knn_kernel<<<2048, 1024, 0, stream>>>(x, idx);
  prep_kernel<<<2224, 256, 0, stream>>>(W2, W3, W4, W5, W2T, W3T, W4T, W5T);
  edge_kernel<<<8192, 256, 0, stream>>>(x, idx, W1, g1, b1, W2T, g2, b2,
                                        W3T, g3, b3, W4T, g4, b4, hc);
  gemm5_kernel<<<2048, 256, 0, stream>>>(hc, W5T, g5, b5, red);
  reduce_g_kernel<<<32, 256, 0, stream>>>(red, gbuf);
  fc1_kernel<<<16, 256, 0, stream>>>(gbuf, L1, g6, b6, f1);
  fc2_kernel<<<8, 256, 0, stream>>>(f1, L2, L2b, g7, b7, f2);
  fc3_kernel<<<4, 256, 0, stream>>>(f2, L3, L3b, (float*)d_out);
}

// Round 5
// 470.756 us; speedup vs baseline: 3.4390x; 1.3992x over previous
//
#include <hip/hip_runtime.h>
#include <hip/hip_bf16.h>
#include <hip/hip_fp16.h>

#define NPTS 4096
#define KNB  20
#define EPSB 1e-5f

typedef _Float16 half8 __attribute__((ext_vector_type(8)));
typedef float    f32x4 __attribute__((ext_vector_type(4)));

__device__ __forceinline__ f32x4 mfma16(half8 a, half8 b, f32x4 c){
  return __builtin_amdgcn_mfma_f32_16x16x32_f16(a, b, c, 0, 0, 0);
}

// A fragment from LDS, row-major [rows][C] fp16, XOR-swizzled by (row&7)<<3 elements.
__device__ __forceinline__ half8 loadA_lds(const _Float16* buf, int C, int mt, int ks, int lane){
  int row = mt*16 + (lane & 15);
  int k0  = ks*32 + (lane >> 4)*8;
  int e   = (row*C + k0) ^ ((row & 7) << 3);
  return *reinterpret_cast<const half8*>(&buf[e]);
}

// B fragment from global, WT is [N_out][K] fp16 (pre-transposed weight)
__device__ __forceinline__ half8 loadB_g(const _Float16* WT, int K, int nt, int ks, int lane){
  int col = nt*16 + (lane & 15);
  int k0  = ks*32 + (lane >> 4)*8;
  return *reinterpret_cast<const half8*>(&WT[col*K + k0]);
}

// ---------------- KNN ---------------- (unchanged from round 4)
__global__ __launch_bounds__(1024)
void knn_kernel(const float* __restrict__ x, int* __restrict__ idx_out){
  __shared__ float4 spts[NPTS];           // (x,y,z,xx) 64KB
  int b  = blockIdx.x >> 8;
  int r0 = (blockIdx.x & 255) << 4;
  const float* xb = x + (size_t)b*NPTS*3;
  for (int t = threadIdx.x; t < NPTS; t += 1024){
    float px = xb[t*3+0], py = xb[t*3+1], pz = xb[t*3+2];
    spts[t] = make_float4(px, py, pz, px*px + py*py + pz*pz);
  }
  __syncthreads();
  int wave = threadIdx.x >> 6, lane = threadIdx.x & 63;
  int i = r0 + wave;
  float4 pi = spts[i];
  float b1 = -INFINITY, b2 = -INFINITY, b3 = -INFINITY;
  int   i1 = 0, i2 = 0, i3 = 0;
  #pragma unroll 8
  for (int t = 0; t < 64; ++t){
    int j = (t << 6) + lane;
    float4 q = spts[j];
    float d = 2.f*(pi.x*q.x + pi.y*q.y + pi.z*q.z) - pi.w - q.w;
    if (d > b1){ b3=b2; i3=i2; b2=b1; i2=i1; b1=d; i1=j; }
    else if (d > b2){ b3=b2; i3=i2; b2=d; i2=j; }
    else if (d > b3){ b3=d; i3=j; }
  }
  unsigned long long rem = 0ull;
  size_t obase = ((size_t)b*NPTS + i)*KNB;
  #pragma unroll 1
  for (int kk = 0; kk < KNB; ++kk){
    float bv = b1; int bi = i1;
    #pragma unroll
    for (int m = 32; m > 0; m >>= 1){
      float ov = __shfl_xor(bv, m);
      int   oi = __shfl_xor(bi, m);
      if (ov > bv || (ov == bv && oi < bi)){ bv = ov; bi = oi; }
    }
    if (lane == 0) idx_out[obase + kk] = bi;
    if ((bi & 63) == lane){
      rem |= 1ull << (bi >> 6);
      b1 = b2; i1 = i2; b2 = b3; i2 = i3; b3 = -INFINITY; i3 = 0;
      if (b1 == -INFINITY){
        #pragma unroll 8
        for (int t = 0; t < 64; ++t){
          if (rem & (1ull << t)) continue;
          int j = (t << 6) + lane;
          float4 q = spts[j];
          float d = 2.f*(pi.x*q.x + pi.y*q.y + pi.z*q.z) - pi.w - q.w;
          if (d > b1){ b3=b2; i3=i2; b2=b1; i2=i1; b1=d; i1=j; }
          else if (d > b2){ b3=b2; i3=i2; b2=d; i2=j; }
          else if (d > b3){ b3=d; i3=j; }
        }
      }
    }
  }
}

// ---------------- weight prep: fp32 [K][O] -> fp16 [O][K] ----------------
__global__ __launch_bounds__(256)
void prep_kernel(const float* __restrict__ W2, const float* __restrict__ W3,
                 const float* __restrict__ W4, const float* __restrict__ W5,
                 _Float16* __restrict__ W2T, _Float16* __restrict__ W3T,
                 _Float16* __restrict__ W4T, _Float16* __restrict__ W5T){
  int t = blockIdx.x*256 + threadIdx.x;
  if (t < 4096){ int o=t>>6, k=t&63;                W2T[t] = (_Float16)W2[k*64+o]; }
  else if (t < 12288){ int u=t-4096;  int o=u>>6, k=u&63;   W3T[u] = (_Float16)W3[k*128+o]; }
  else if (t < 45056){ int u=t-12288; int o=u>>7, k=u&127;  W4T[u] = (_Float16)W4[k*256+o]; }
  else if (t < 569344){ int u=t-45056; int o=u>>9, k=u&511; W5T[u] = (_Float16)W5[k*1024+o]; }
}

// ---------------- fused edge layers 1-4, in-register max-over-K ----------------
// 4 points/block, 256 thr (4 waves). Rows 0..79; MFMA D row = mt*16+g*4+rr
// (g=lane>>4, rr<=3) -> the point boundary (row/20) splits exactly at a g
// boundary per mt: mt0->p0, mt1 g>=1->p1, mt2 g>=2->p2, mt3 g>=3->p3, mt4->p3.
// So max-over-K runs on MFMA outputs in regs (static buckets + 2 shfl),
// never re-reading LDS. Layer-4 output never touches LDS at all.
// LDS = exactly 40960B -> 4 blocks/CU.
__device__ __forceinline__ void bucket(int mt, bool c1, bool c2, bool c3, float v,
                                       float& p0, float& p1, float& p2, float& p3){
  if (mt == 0)      p0 = fmaxf(p0, v);
  else if (mt == 4) p3 = fmaxf(p3, v);
  else if (mt == 1){ p1 = fmaxf(p1, c1 ? v : -INFINITY); p0 = fmaxf(p0, c1 ? -INFINITY : v); }
  else if (mt == 2){ p2 = fmaxf(p2, c2 ? v : -INFINITY); p1 = fmaxf(p1, c2 ? -INFINITY : v); }
  else             { p3 = fmaxf(p3, c3 ? v : -INFINITY); p2 = fmaxf(p2, c3 ? -INFINITY : v); }
}

__device__ __forceinline__ void reduce_write_x(float p0, float p1, float p2, float p3,
                                               _Float16* __restrict__ hc, size_t gp0,
                                               int off, int g, int c){
  p0 = fmaxf(p0, __shfl_xor(p0, 16)); p0 = fmaxf(p0, __shfl_xor(p0, 32));
  p1 = fmaxf(p1, __shfl_xor(p1, 16)); p1 = fmaxf(p1, __shfl_xor(p1, 32));
  p2 = fmaxf(p2, __shfl_xor(p2, 16)); p2 = fmaxf(p2, __shfl_xor(p2, 32));
  p3 = fmaxf(p3, __shfl_xor(p3, 16)); p3 = fmaxf(p3, __shfl_xor(p3, 32));
  float v = (g == 0) ? p0 : (g == 1) ? p1 : (g == 2) ? p2 : p3;
  hc[(gp0 + g)*512 + off + c] = (_Float16)v;
}

__global__ __launch_bounds__(256)
void edge_kernel(const float* __restrict__ x, const int* __restrict__ knn,
                 const float* __restrict__ W1, const float* __restrict__ g1, const float* __restrict__ b1,
                 const _Float16* __restrict__ W2T, const float* __restrict__ g2, const float* __restrict__ b2,
                 const _Float16* __restrict__ W3T, const float* __restrict__ g3, const float* __restrict__ b3,
                 const _Float16* __restrict__ W4T, const float* __restrict__ g4, const float* __restrict__ b4,
                 _Float16* __restrict__ hc){
  __shared__ __align__(16) char smem[40960];
  _Float16* hb1 = (_Float16*)(smem);             // 80*64*2  = 10240
  _Float16* hb2 = (_Float16*)(smem + 10240);     // 80*64*2  = 10240
  _Float16* hb3 = (_Float16*)(smem + 20480);     // 80*128*2 = 20480
  float*    h0f = (float*)(smem + 20480);        // aliases hb3 head: 80*4*4 = 1280 (dead before hb3 written)
  float*    h0c = (float*)(smem + 20480 + 1280); // 4*4*4 = 64
  const float rs = 1.f / sqrtf(1.f + EPSB);
  int gp0 = blockIdx.x << 2;
  int b   = gp0 >> 12;
  int n0  = gp0 & (NPTS-1);
  const float* xb = x + (size_t)b*NPTS*3;
  int tid = threadIdx.x;
  if (tid < 80){
    int p = tid / 20, k = tid % 20;
    int nb = knn[((size_t)b*NPTS + n0 + p)*KNB + k];
    h0f[tid*4+0] = xb[nb*3+0];
    h0f[tid*4+1] = xb[nb*3+1];
    h0f[tid*4+2] = xb[nb*3+2];
  } else if (tid < 96){
    int u = tid - 80; int p = u >> 2, c = u & 3;
    if (c < 3) h0c[p*4+c] = xb[(n0+p)*3+c];
  }
  __syncthreads();
  int w = tid >> 6, lane = tid & 63, g = lane >> 4, cc = lane & 15;
  bool c1 = (g >= 1), c2 = (g >= 2), c3 = (g >= 3);
  // ---- layer 1: wave w owns point w's 20 rows; x1 max inline ----
  {
    int col = lane;
    float sc = g1[col]*rs, bs = b1[col];
    float w0=W1[col], w1_=W1[64+col], w2_=W1[128+col], w3_=W1[192+col], w4_=W1[256+col], w5_=W1[320+col];
    float cx = h0c[w*4+0], cy = h0c[w*4+1], cz = h0c[w*4+2];
    float m1 = -INFINITY;
    #pragma unroll 5
    for (int k = 0; k < KNB; ++k){
      int r = w*20 + k;
      float a = h0f[r*4+0]*w0 + h0f[r*4+1]*w1_ + h0f[r*4+2]*w2_ + cx*w3_ + cy*w4_ + cz*w5_;
      float vv = a*sc + bs; vv = vv > 0.f ? vv : 0.2f*vv;
      hb1[((r<<6)+col) ^ ((r&7)<<3)] = (_Float16)vv;
      m1 = fmaxf(m1, vv);
    }
    hc[(size_t)(gp0 + w)*512 + col] = (_Float16)m1;
  }
  __syncthreads();
  // ---- layer 2: [80,64]@[64,64]; wave w owns cols w*16..+16 ----
  {
    int colg = (w<<4) + cc;
    float sc = g2[colg]*rs, bs = b2[colg];
    half8 bf0 = loadB_g(W2T, 64, w, 0, lane);
    half8 bf1 = loadB_g(W2T, 64, w, 1, lane);
    f32x4 acc[5];
    #pragma unroll
    for (int mt = 0; mt < 5; ++mt){
      f32x4 a = {0.f,0.f,0.f,0.f};
      a = mfma16(loadA_lds(hb1,64,mt,0,lane), bf0, a);
      a = mfma16(loadA_lds(hb1,64,mt,1,lane), bf1, a);
      acc[mt] = a;
    }
    float p0=-INFINITY, p1=-INFINITY, p2=-INFINITY, p3=-INFINITY;
    #pragma unroll
    for (int mt = 0; mt < 5; ++mt){
      #pragma unroll
      for (int rr = 0; rr < 4; ++rr){
        int row = mt*16 + g*4 + rr;
        float vv = acc[mt][rr]*sc + bs; vv = vv > 0.f ? vv : 0.2f*vv;
        hb2[(row*64 + colg) ^ ((row&7)<<3)] = (_Float16)vv;
        bucket(mt, c1, c2, c3, vv, p0, p1, p2, p3);
      }
    }
    reduce_write_x(p0,p1,p2,p3, hc, gp0, 64 + (w<<4), g, cc);
  }
  __syncthreads();
  // ---- layer 3: [80,64]@[64,128]; wave w owns ntiles 2w,2w+1 ----
  #pragma unroll
  for (int tt = 0; tt < 2; ++tt){
    int nt = (w<<1) + tt;
    int colg = (nt<<4) + cc;
    float sc = g3[colg]*rs, bs = b3[colg];
    half8 bf0 = loadB_g(W3T, 64, nt, 0, lane);
    half8 bf1 = loadB_g(W3T, 64, nt, 1, lane);
    f32x4 acc[5];
    #pragma unroll
    for (int mt = 0; mt < 5; ++mt){
      f32x4 a = {0.f,0.f,0.f,0.f};
      a = mfma16(loadA_lds(hb2,64,mt,0,lane), bf0, a);
      a = mfma16(loadA_lds(hb2,64,mt,1,lane), bf1, a);
      acc[mt] = a;
    }
    float p0=-INFINITY, p1=-INFINITY, p2=-INFINITY, p3=-INFINITY;
    #pragma unroll
    for (int mt = 0; mt < 5; ++mt){
      #pragma unroll
      for (int rr = 0; rr < 4; ++rr){
        int row = mt*16 + g*4 + rr;
        float vv = acc[mt][rr]*sc + bs; vv = vv > 0.f ? vv : 0.2f*vv;
        hb3[(row*128 + colg) ^ ((row&7)<<3)] = (_Float16)vv;
        bucket(mt, c1, c2, c3, vv, p0, p1, p2, p3);
      }
    }
    reduce_write_x(p0,p1,p2,p3, hc, gp0, 128 + (nt<<4), g, cc);
  }
  __syncthreads();
  // ---- layer 4: [80,128]@[128,256]; pure reg output, no LDS, no barriers ----
  #pragma unroll 1
  for (int ch = 0; ch < 4; ++ch){
    int ntg = (ch<<2) + w;
    int colg = (ntg<<4) + cc;
    float sc = g4[colg]*rs, bs = b4[colg];
    half8 bw[4];
    #pragma unroll
    for (int ks = 0; ks < 4; ++ks) bw[ks] = loadB_g(W4T, 128, ntg, ks, lane);
    f32x4 acc[5] = {};
    #pragma unroll
    for (int ks = 0; ks < 4; ++ks)
      #pragma unroll
      for (int mt = 0; mt < 5; ++mt)
        acc[mt] = mfma16(loadA_lds(hb3,128,mt,ks,lane), bw[ks], acc[mt]);
    float p0=-INFINITY, p1=-INFINITY, p2=-INFINITY, p3=-INFINITY;
    #pragma unroll
    for (int mt = 0; mt < 5; ++mt){
      #pragma unroll
      for (int rr = 0; rr < 4; ++rr){
        float vv = acc[mt][rr]*sc + bs; vv = vv > 0.f ? vv : 0.2f*vv;
        bucket(mt, c1, c2, c3, vv, p0, p1, p2, p3);
      }
    }
    reduce_write_x(p0,p1,p2,p3, hc, gp0, 256 + (ntg<<4), g, cc);
  }
}

// ---------------- layer 5 GEMM + pooling partials ---------------- (unchanged)
__global__ __launch_bounds__(256)
void gemm5_kernel(const _Float16* __restrict__ hc, const _Float16* __restrict__ W5T,
                  const float* __restrict__ g5, const float* __restrict__ b5,
                  float* __restrict__ red){
  __shared__ __align__(16) _Float16 sA[64*512];   // 64KB
  int rowblk = blockIdx.x >> 2;
  int colblk = blockIdx.x & 3;
  int row0 = rowblk << 6;
  #pragma unroll 1
  for (int it = 0; it < 16; ++it){
    int eoff = it*2048 + threadIdx.x*8;
    int row = eoff >> 9;
    int ine = eoff & 511;
    half8 vsrc = *reinterpret_cast<const half8*>(
        &hc[(size_t)(row0 + row)*512 + (ine ^ ((row & 7) << 3))]);
    *reinterpret_cast<half8*>(&sA[(row << 9) + ine]) = vsrc;
  }
  __syncthreads();
  int wave = threadIdx.x >> 6, lane = threadIdx.x & 63;
  f32x4 acc[4][4] = {};
  #pragma unroll 1
  for (int ks = 0; ks < 16; ++ks){
    half8 af[4];
    #pragma unroll
    for (int mt = 0; mt < 4; ++mt) af[mt] = loadA_lds(sA, 512, mt, ks, lane);
    #pragma unroll
    for (int nt = 0; nt < 4; ++nt){
      int ntg = (colblk<<4) + (wave<<2) + nt;
      half8 bf = loadB_g(W5T, 512, ntg, ks, lane);
      #pragma unroll
      for (int mt = 0; mt < 4; ++mt)
        acc[mt][nt] = mfma16(af[mt], bf, acc[mt][nt]);
    }
  }
  int batch = row0 >> 12;
  int chunk = (row0 & (NPTS-1)) >> 6;
  const float rs = 1.f/sqrtf(1.f+EPSB);
  #pragma unroll
  for (int nt = 0; nt < 4; ++nt){
    int ntg = (colblk<<4) + (wave<<2) + nt;
    int colg = (ntg<<4) + (lane & 15);
    float sc = g5[colg]*rs, bs = b5[colg];
    float vmax = -INFINITY, vsum = 0.f;
    #pragma unroll
    for (int mt = 0; mt < 4; ++mt){
      #pragma unroll
      for (int r = 0; r < 4; ++r){
        float vv = acc[mt][nt][r]*sc + bs;
        vv = vv>0.f ? vv : 0.2f*vv;
        vmax = fmaxf(vmax, vv); vsum += vv;
      }
    }
    vmax = fmaxf(vmax, __shfl_xor(vmax, 16)); vsum += __shfl_xor(vsum, 16);
    vmax = fmaxf(vmax, __shfl_xor(vmax, 32)); vsum += __shfl_xor(vsum, 32);
    if ((lane >> 4) == 0){
      size_t base = (size_t)((batch<<6) + chunk)*2048;
      red[base + colg] = vmax;
      red[base + 1024 + colg] = vsum;
    }
  }
}

__global__ __launch_bounds__(256)
void reduce_g_kernel(const float* __restrict__ red, float* __restrict__ g){
  int t = blockIdx.x*256 + threadIdx.x;   // 8192
  int b = t >> 10, col = t & 1023;
  float m = -INFINITY, s = 0.f;
  #pragma unroll 4
  for (int c = 0; c < 64; ++c){
    size_t base = (size_t)((b<<6)+c)*2048;
    m = fmaxf(m, red[base + col]);
    s += red[base + 1024 + col];
  }
  g[(b<<11) + col]        = m;
  g[(b<<11) + 1024 + col] = s * (1.f/4096.f);
}

// ---------------- head MLP: split-K, coalesced o-major loads ----------------
__global__ __launch_bounds__(256)
void fc1_kernel(const float* __restrict__ g, const float* __restrict__ L1,
                const float* __restrict__ g6, const float* __restrict__ b6,
                float* __restrict__ f1){
  __shared__ float part[4][64];
  int b  = blockIdx.x >> 3;               // 8 batches x 8 ogroups
  int og = blockIdx.x & 7;
  int o  = (og << 6) + (threadIdx.x & 63);
  int kg = threadIdx.x >> 6;              // 4 k-groups x 512
  const float* gb = g + (b << 11);
  float acc = 0.f;
  #pragma unroll 8
  for (int k = kg*512; k < kg*512 + 512; ++k) acc += gb[k]*L1[k*512 + o];
  part[kg][threadIdx.x & 63] = acc;
  __syncthreads();
  if (threadIdx.x < 64){
    float s = part[0][threadIdx.x] + part[1][threadIdx.x] + part[2][threadIdx.x] + part[3][threadIdx.x];
    float v = s*(g6[o]/sqrtf(1.f+EPSB)) + b6[o];
    f1[(b<<9) + o] = v > 0.f ? v : 0.2f*v;
  }
}

__global__ __launch_bounds__(256)
void fc2_kernel(const float* __restrict__ f1, const float* __restrict__ L2, const float* __restrict__ L2b,
                const float* __restrict__ g7, const float* __restrict__ b7, float* __restrict__ f2){
  __shared__ float part[4][64];
  int b  = blockIdx.x >> 2;               // 8 batches x 4 ogroups
  int og = blockIdx.x & 3;
  int o  = (og << 6) + (threadIdx.x & 63);
  int kg = threadIdx.x >> 6;              // 4 k-groups x 128
  const float* fb = f1 + (b << 9);
  float acc = 0.f;
  #pragma unroll 8
  for (int k = kg*128; k < kg*128 + 128; ++k) acc += fb[k]*L2[k*256 + o];
  part[kg][threadIdx.x & 63] = acc;
  __syncthreads();
  if (threadIdx.x < 64){
    float s = part[0][threadIdx.x] + part[1][threadIdx.x] + part[2][threadIdx.x] + part[3][threadIdx.x];
    float v = (s + L2b[o])*(g7[o]/sqrtf(1.f+EPSB)) + b7[o];
    f2[(b<<8) + o] = v > 0.f ? v : 0.2f*v;
  }
}

__global__ __launch_bounds__(256)
void fc3_kernel(const float* __restrict__ f2, const float* __restrict__ L3, const float* __restrict__ L3b,
                float* __restrict__ out){
  __shared__ float part[2][128];
  int b  = blockIdx.x;                    // 8 batches
  int o  = threadIdx.x & 127;
  int kg = threadIdx.x >> 7;              // 2 k-groups x 128
  const float* fb = f2 + (b << 8);
  float acc = 0.f;
  #pragma unroll 8
  for (int k = kg*128; k < kg*128 + 128; ++k) acc += fb[k]*L3[k*128 + o];
  part[kg][o] = acc;
  __syncthreads();
  if (threadIdx.x < 128)
    out[(b<<7) + o] = part[0][o] + part[1][o] + L3b[o];
}

extern "C" void kernel_launch(void* const* d_in, const int* in_sizes, int n_in,
                              void* d_out, int out_size, void* d_ws, size_t ws_size,
                              hipStream_t stream){
  const float* x  = (const float*)d_in[0];
  const float* W1 = (const float*)d_in[1];
  const float* g1 = (const float*)d_in[2];  const float* b1 = (const float*)d_in[3];
  const float* W2 = (const float*)d_in[4];
  const float* g2 = (const float*)d_in[5];  const float* b2 = (const float*)d_in[6];
  const float* W3 = (const float*)d_in[7];
  const float* g3 = (const float*)d_in[8];  const float* b3 = (const float*)d_in[9];
  const float* W4 = (const float*)d_in[10];
  const float* g4 = (const float*)d_in[11]; const float* b4 = (const float*)d_in[12];
  const float* W5 = (const float*)d_in[13];
  const float* g5 = (const float*)d_in[14]; const float* b5 = (const float*)d_in[15];
  const float* L1 = (const float*)d_in[16];
  const float* g6 = (const float*)d_in[17]; const float* b6 = (const float*)d_in[18];
  const float* L2 = (const float*)d_in[19]; const float* L2b = (const float*)d_in[20];
  const float* g7 = (const float*)d_in[21]; const float* b7 = (const float*)d_in[22];
  const float* L3 = (const float*)d_in[23]; const float* L3b = (const float*)d_in[24];

  char* ws = (char*)d_ws;
  int*      idx  = (int*)(ws + 0);                 // 2,621,440 B
  _Float16* hc   = (_Float16*)(ws + 2621440);      // 33,554,432 B
  _Float16* W2T  = (_Float16*)(ws + 36175872);     // 8,192 B
  _Float16* W3T  = (_Float16*)(ws + 36184064);     // 16,384 B
  _Float16* W4T  = (_Float16*)(ws + 36200448);     // 65,536 B
  _Float16* W5T  = (_Float16*)(ws + 36265984);     // 1,048,576 B
  float*    red  = (float*)(ws + 37314560);        // 4,194,304 B
  float*    gbuf = (float*)(ws + 41508864);        // 65,536 B
  float*    f1   = (float*)(ws + 41574400);        // 16,384 B
  float*    f2   = (float*)(ws + 41590784);        // 8,192 B

  knn_kernel<<<2048, 1024, 0, stream>>>(x, idx);
  prep_kernel<<<2224, 256, 0, stream>>>(W2, W3, W4, W5, W2T, W3T, W4T, W5T);
  edge_kernel<<<8192, 256, 0, stream>>>(x, idx, W1, g1, b1, W2T, g2, b2,
                                        W3T, g3, b3, W4T, g4, b4, hc);
  gemm5_kernel<<<2048, 256, 0, stream>>>(hc, W5T, g5, b5, red);
  reduce_g_kernel<<<32, 256, 0, stream>>>(red, gbuf);
  fc1_kernel<<<64, 256, 0, stream>>>(gbuf, L1, g6, b6, f1);
  fc2_kernel<<<32, 256, 0, stream>>>(f1, L2, L2b, g7, b7, f2);
  fc3_kernel<<<8, 256, 0, stream>>>(f2, L3, L3b, (float*)d_out);
}